// Round 4
// baseline (285.212 us; speedup 1.0000x reference)
//
#include <hip/hip_runtime.h>
#include <math.h>

#define B_ 8
#define L_ 200
#define H_ 128
#define NH_ 2
#define HD_ 64
#define LP_ 256   // padded L (pad region never zeroed; OOB contributions discarded)
#define TV_ 32    // time vocab
#define NBLK_ (B_ * (L_ / 2))   // 800 blocks; 4 blocks/CU cap => 1024 slots, all co-resident

// ---------------- single fused kernel (flag-based batch dependency) ----------------
// grid = 800 blocks x 256 threads (4 waves). __launch_bounds__(256,4) caps VGPR at 128
// -> 4 blocks/CU -> all 800 blocks co-resident (deadlock-free spin by construction).
// Phase 0: this block's 2 rows -> Q (LDS), K^T + kpos, V + vpos (workspace).
//          release-store flags[bid]=1 (agent scope).
// Wait:    acquire-poll the 100 flags of this batch; __threadfence() invalidates
//          stale XCD-L2 lines so plain K/V loads below are coherent.
// Phase 1: attention + time-attn + out-proj + residual + LayerNorm (round-2 code).
__global__ __launch_bounds__(256, 4)
void fused_kernel(const float* __restrict__ X,
                  const float* __restrict__ Wq, const float* __restrict__ bq,
                  const float* __restrict__ Wk, const float* __restrict__ bk,
                  const float* __restrict__ Wv, const float* __restrict__ bv,
                  const float* __restrict__ kpt, const float* __restrict__ vpt,
                  const int*   __restrict__ tseq, const float* __restrict__ mask,
                  const float* __restrict__ ktt, const float* __restrict__ vtt,
                  const float* __restrict__ Wd,  const float* __restrict__ bd,
                  const float* __restrict__ g,   const float* __restrict__ bb,
                  float* Kt, float* Vp, unsigned* flags, float* __restrict__ out){
    const int b  = blockIdx.x / (L_ / 2);
    const int q0 = (blockIdx.x % (L_ / 2)) * 2;

    __shared__ __align__(16) float qs   [2][2][HD_];   // Q stays on-chip
    __shared__ __align__(16) float xs   [2][H_];
    __shared__ float qkt_s[4][TV_];
    __shared__ float ss_s [4][TV_];
    __shared__ __align__(16) float ps_s [4][LP_];
    __shared__ __align__(16) float ctx_s[2][H_];
    __shared__ float redA[4], redB[4];

    // ---- phase 0: QKV projection for rows q0, q0+1 (thread j: r=j>>7, c=j&127)
    {
        const int j = threadIdx.x, r = j >> 7, c = j & 127;
        xs[r][c] = X[(b * L_ + q0 + r) * H_ + c];
        __syncthreads();
        float aq = 0.f, ak = 0.f, av = 0.f;
        const float4* xv4 = (const float4*)xs[r];
        #pragma unroll 2
        for (int i4 = 0; i4 < H_ / 4; ++i4) {
            const float4 xv = xv4[i4];
            const int i = i4 * 4;
            aq += xv.x * Wq[(i + 0) * H_ + c] + xv.y * Wq[(i + 1) * H_ + c]
                + xv.z * Wq[(i + 2) * H_ + c] + xv.w * Wq[(i + 3) * H_ + c];
            ak += xv.x * Wk[(i + 0) * H_ + c] + xv.y * Wk[(i + 1) * H_ + c]
                + xv.z * Wk[(i + 2) * H_ + c] + xv.w * Wk[(i + 3) * H_ + c];
            av += xv.x * Wv[(i + 0) * H_ + c] + xv.y * Wv[(i + 1) * H_ + c]
                + xv.z * Wv[(i + 2) * H_ + c] + xv.w * Wv[(i + 3) * H_ + c];
        }
        const int h = c >> 6, d = c & 63, l = q0 + r;
        qs[r][h][d] = aq + bq[c];                                     // LDS only
        Kt[((b * NH_ + h) * HD_ + d) * LP_ + l] = ak + bk[c] + kpt[l * H_ + c];
        Vp[((b * NH_ + h) * L_ + l) * HD_ + d]  = av + bv[c] + vpt[l * H_ + c];
    }
    __syncthreads();   // all K/V stores of this block complete (vmcnt drained)
    if (threadIdx.x == 0)   // release: block's K/V visible before flag turns 1
        __hip_atomic_store(&flags[blockIdx.x], 1u, __ATOMIC_RELEASE, __HIP_MEMORY_SCOPE_AGENT);
    // wait for this batch's 100 producer blocks (threads 0..99 poll one flag each)
    {
        const int base = b * (L_ / 2);
        for (int i = threadIdx.x; i < L_ / 2; i += 256)
            while (__hip_atomic_load(&flags[base + i], __ATOMIC_ACQUIRE,
                                     __HIP_MEMORY_SCOPE_AGENT) == 0u)
                __builtin_amdgcn_s_sleep(2);
    }
    __syncthreads();
    __threadfence();   // acquire side for ALL threads: invalidate stale XCD-L2 lines

    // ---- phase 1: attention. wave w: head h = w&1, q-row qr = w>>1.
    const int w = threadIdx.x >> 6, lane = threadIdx.x & 63;
    const int h = w & 1, qr = w >> 1;
    const int q = q0 + qr;
    const int bh = b * NH_ + h;

    if (lane < TV_) ss_s[w][lane] = 0.f;   // wave-private

    // qkt[bkt] = dot(q, ktt[bkt, head slice]); 2 lanes per bucket, from L2
    {
        const int bkt = lane >> 1, half = lane & 1;
        const float4* kr4  = (const float4*)(ktt + bkt * H_ + h * HD_ + half * 32);
        const float4* qv4p = (const float4*)(&qs[qr][h][half * 32]);
        float a = 0.f;
        #pragma unroll
        for (int d4 = 0; d4 < 8; ++d4) {
            const float4 kv = kr4[d4];
            const float4 qv = qv4p[d4];
            a += qv.x * kv.x + qv.y * kv.y + qv.z * kv.z + qv.w * kv.w;
        }
        a += __shfl_xor(a, 1);
        if (half == 0) qkt_s[w][bkt] = a;   // same-wave LDS, ordered
    }

    // ---- phase A: lane handles k = 4*lane .. 4*lane+3
    const float4* kt4 = (const float4*)(Kt + (size_t)bh * HD_ * LP_);
    const float4* qv4 = (const float4*)qs[qr][h];
    float4 s4 = make_float4(0.f, 0.f, 0.f, 0.f);
    #pragma unroll 4
    for (int d4 = 0; d4 < HD_ / 4; ++d4) {
        const float4 qq = qv4[d4];
        const float4 k0 = kt4[(d4 * 4 + 0) * (LP_ / 4) + lane];
        const float4 k1 = kt4[(d4 * 4 + 1) * (LP_ / 4) + lane];
        const float4 k2 = kt4[(d4 * 4 + 2) * (LP_ / 4) + lane];
        const float4 k3 = kt4[(d4 * 4 + 3) * (LP_ / 4) + lane];
        s4.x += qq.x * k0.x + qq.y * k1.x + qq.z * k2.x + qq.w * k3.x;
        s4.y += qq.x * k0.y + qq.y * k1.y + qq.z * k2.y + qq.w * k3.y;
        s4.z += qq.x * k0.z + qq.y * k1.z + qq.z * k2.z + qq.w * k3.z;
        s4.w += qq.x * k0.w + qq.y * k1.w + qq.z * k2.w + qq.w * k3.w;
    }
    float sv[4] = {s4.x, s4.y, s4.z, s4.w};
    const int k0i = lane * 4;
    float mx = -INFINITY;
    if (k0i < L_) {  // lanes 0..49; rows 800B-aligned -> float4/int4 ok
        const float4 m4 = ((const float4*)(mask + ((size_t)(b * L_ + q)) * L_))[lane];
        const int4   t4 = ((const int4*)(tseq + b * L_))[lane];
        const int    tq = tseq[b * L_ + q];
        const float mv[4] = {m4.x, m4.y, m4.z, m4.w};
        const int   tk[4] = {t4.x, t4.y, t4.z, t4.w};
        #pragma unroll
        for (int jj = 0; jj < 4; ++jj) {
            int dt = tq - tk[jj]; if (dt < 0) dt = -dt;
            int ib = (int)log1pf((float)dt); if (ib > TV_ - 1) ib = TV_ - 1;
            const float s = (sv[jj] + qkt_s[w][ib]) * 0.125f + mv[jj];
            sv[jj] = s;
            atomicAdd(&ss_s[w][ib], s);     // pre-softmax bucket sums (wave-private)
            if (s > mx) mx = s;
        }
    } else {
        sv[0] = sv[1] = sv[2] = sv[3] = -INFINITY;  // Kt pad garbage discarded
    }
    #pragma unroll
    for (int off = 32; off; off >>= 1) { const float o = __shfl_xor(mx, off); if (o > mx) mx = o; }
    float sum = 0.f, ev[4];
    #pragma unroll
    for (int jj = 0; jj < 4; ++jj) {
        const float e = (k0i + jj < L_) ? __expf(sv[jj] - mx) : 0.f;
        ev[jj] = e; sum += e;
    }
    #pragma unroll
    for (int off = 32; off; off >>= 1) sum += __shfl_xor(sum, off);
    ((float4*)ps_s[w])[lane] = make_float4(ev[0], ev[1], ev[2], ev[3]);
    const float inv = 1.f / sum;

    // ---- phase B (PV): lane = (kk = k-group, d4 = d-quad); float4 V loads
    {
        const int kk = lane >> 4, d4 = lane & 15;
        const float4* vp4 = (const float4*)(Vp + (size_t)bh * L_ * HD_);
        float4 c4 = make_float4(0.f, 0.f, 0.f, 0.f);
        #pragma unroll 5
        for (int kb = 0; kb < L_; kb += 4) {
            const float  p  = ps_s[w][kb + kk];               // same-wave LDS, ordered
            const float4 vv = vp4[(kb + kk) * (HD_ / 4) + d4];
            c4.x += p * vv.x; c4.y += p * vv.y; c4.z += p * vv.z; c4.w += p * vv.w;
        }
        #pragma unroll
        for (int off = 16; off <= 32; off <<= 1) {            // butterfly over kk
            c4.x += __shfl_xor(c4.x, off);
            c4.y += __shfl_xor(c4.y, off);
            c4.z += __shfl_xor(c4.z, off);
            c4.w += __shfl_xor(c4.w, off);
        }
        if (kk == 0) {
            c4.x *= inv; c4.y *= inv; c4.z *= inv; c4.w *= inv;
            *(float4*)&ctx_s[qr][h * HD_ + d4 * 4] = c4;
        }
    }
    // time-ctx: lane = d, vtt straight from L2; raw pre-softmax scores
    {
        float tc = 0.f;
        #pragma unroll 8
        for (int i = 0; i < TV_; ++i) tc += ss_s[w][i] * vtt[i * H_ + h * HD_ + lane];
        ctx_s[qr][h * HD_ + lane] += tc;   // same-wave LDS after float4 store: ordered
    }
    __syncthreads();   // join: out-proj reads full ctx rows across waves

    // ---- out projection + residual + one-pass LayerNorm: 1 row per 128 thr
    const int rr = threadIdx.x >> 7, j = threadIdx.x & 127;
    const float4* cr = (const float4*)ctx_s[rr];
    float acc = 0.f;
    #pragma unroll 8
    for (int i4 = 0; i4 < H_ / 4; ++i4) {
        const float4 xa = cr[i4];
        const int i = i4 * 4;
        acc += xa.x * Wd[(i + 0) * H_ + j];
        acc += xa.y * Wd[(i + 1) * H_ + j];
        acc += xa.z * Wd[(i + 2) * H_ + j];
        acc += xa.w * Wd[(i + 3) * H_ + j];
    }
    const int row = b * L_ + q0 + rr;
    const float x = acc + bd[j] + xs[rr][j];       // residual from LDS copy of X
    float s1 = x, s2 = x * x;
    #pragma unroll
    for (int off = 32; off; off >>= 1) { s1 += __shfl_xor(s1, off); s2 += __shfl_xor(s2, off); }
    if (lane == 0) { redA[w] = s1; redB[w] = s2; }
    __syncthreads();
    const float mean = (redA[2 * rr] + redA[2 * rr + 1]) * (1.f / H_);
    const float ex2  = (redB[2 * rr] + redB[2 * rr + 1]) * (1.f / H_);
    const float var  = ex2 - mean * mean;
    out[row * H_ + j] = (x - mean) * rsqrtf(var + 1e-12f) * g[j] + bb[j];
}

// ---------------------------------------------------------------- launch
extern "C" void kernel_launch(void* const* d_in, const int* in_sizes, int n_in,
                              void* d_out, int out_size, void* d_ws, size_t ws_size,
                              hipStream_t stream) {
    const float* X    = (const float*)d_in[0];
    const int*   tseq = (const int*)  d_in[1];
    const float* mask = (const float*)d_in[2];
    const float* Wq = (const float*)d_in[3],  *bq = (const float*)d_in[4];
    const float* Wk = (const float*)d_in[5],  *bk = (const float*)d_in[6];
    const float* Wv = (const float*)d_in[7],  *bv = (const float*)d_in[8];
    const float* Wd = (const float*)d_in[9],  *bd = (const float*)d_in[10];
    const float* g  = (const float*)d_in[11], *bb = (const float*)d_in[12];
    const float* ktt = (const float*)d_in[13], *vtt = (const float*)d_in[14];
    const float* kpt = (const float*)d_in[15], *vpt = (const float*)d_in[16];

    float*    ws    = (float*)d_ws;
    float*    Kt    = ws;                          // B*NH*HD*LP = 262144 floats
    float*    Vp    = Kt + B_ * NH_ * HD_ * LP_;   // B*L*H      = 204800 floats
    unsigned* flags = (unsigned*)(Vp + B_ * L_ * H_);  // 800 uints

    // zero the done-flags (graph-capturable memset node; no reliance on poison)
    hipMemsetAsync(flags, 0, NBLK_ * sizeof(unsigned), stream);

    fused_kernel<<<NBLK_, 256, 0, stream>>>(X, Wq, bq, Wk, bk, Wv, bv, kpt, vpt,
                                            tseq, mask, ktt, vtt, Wd, bd, g, bb,
                                            Kt, Vp, flags, (float*)d_out);
}